// Round 1
// baseline (6702.573 us; speedup 1.0000x reference)
//
#include <hip/hip_runtime.h>
#include <math.h>

// Problem geometry
#define B_SZ 4
#define S_SZ 4096
#define H_DIM 2048
#define M_TOT (B_SZ * S_SZ)   // 16384 token rows
#define K_DIM H_DIM           // 2048

// Output layout (flat floats, reference return order)
#define OUT_TOKC  0           // [4,4096,1]  16384
#define OUT_CTXC  16384       // [4,1]       4
#define OUT_TASKC 16388       // [4,1]       4
#define OUT_SUPW  16392       // [4,4096,4]  65536
#define OUT_DEPTH 81928       // [4,4096,8]  131072
#define OUT_EFF   213000      // [4,4096,1]  16384
#define OUT_MASK  229384      // [4,4096,4]  65536

// Workspace layout (floats)
#define WS_CTXSUM 0           // 8192   (B*H column sums of token_embeddings)
#define WS_HBUF   8192        // 8192   (ctx/task hidden: 2 nets * 4 b * 1024)
#define WS_TOKL   16384       // 16384  (tok logits, atomic-accumulated)
#define WS_EFFL   32768       // 16384  (eff logits)
#define WS_SUPL   49152       // 65536  (sup logits [M,4])
#define WS_DEPL   114688      // 131072 (dep logits [M,8])
#define WS_TOTAL  245760      // ~983 KB

__device__ __forceinline__ float gelu_f(float x) {
    // exact GELU: x * 0.5 * (1 + erf(x / sqrt(2)))  (matches approximate=False)
    return 0.5f * x * (1.0f + erff(x * 0.70710678118654752440f));
}
__device__ __forceinline__ float sigmoid_f(float x) {
    return 1.0f / (1.0f + expf(-x));
}

// ---------------------------------------------------------------------------
// init: zero ctxsum/hbuf, pre-load logit buffers with their output biases
// (ws is re-poisoned 0xAA before every timed launch).
// ---------------------------------------------------------------------------
__global__ __launch_bounds__(256) void init_ws(float* __restrict__ ws,
        const float* __restrict__ tokb2, const float* __restrict__ effb2,
        const float* __restrict__ supb2, const float* __restrict__ depb2) {
    int i = blockIdx.x * 256 + threadIdx.x;
    if (i >= WS_TOTAL) return;
    float v;
    if (i < WS_TOKL)      v = 0.0f;                      // ctxsum + hbuf
    else if (i < WS_EFFL) v = tokb2[0];
    else if (i < WS_SUPL) v = effb2[0];
    else if (i < WS_DEPL) v = supb2[(i - WS_SUPL) & 3];
    else                  v = depb2[(i - WS_DEPL) & 7];
    ws[i] = v;
}

// ---------------------------------------------------------------------------
// context embedding: column sums over S (divided by S at use site)
// grid (8 h-chunks, 32 s-chunks, 4 batches)
// ---------------------------------------------------------------------------
__global__ __launch_bounds__(256) void mean_kernel(const float* __restrict__ X,
                                                   float* __restrict__ ctxsum) {
    int h = blockIdx.x * 256 + threadIdx.x;
    int schunk = blockIdx.y;
    int b = blockIdx.z;
    const float* p = X + ((size_t)b * S_SZ + (size_t)schunk * 128) * H_DIM + h;
    float s = 0.f;
    #pragma unroll 4
    for (int i = 0; i < 128; i++) s += p[(size_t)i * H_DIM];
    atomicAdd(&ctxsum[b * H_DIM + h], s);
}

// ---------------------------------------------------------------------------
// ctx/task MLP hidden layer on the [4, 2048] context embedding
// grid (4 j-chunks, 4 batches, 2 nets)
// ---------------------------------------------------------------------------
__global__ __launch_bounds__(256) void ctx_task_h(const float* __restrict__ ctxsum,
        const float* __restrict__ ctxW1, const float* __restrict__ ctxb1,
        const float* __restrict__ taskW1, const float* __restrict__ taskb1,
        float* __restrict__ hbuf) {
    int j = blockIdx.x * 256 + threadIdx.x;   // 0..1023
    int b = blockIdx.y;
    int net = blockIdx.z;
    const float* W1   = net ? taskW1 : ctxW1;
    const float* bias = net ? taskb1 : ctxb1;
    const float* xs = ctxsum + b * H_DIM;
    float s = 0.f;
    #pragma unroll 8
    for (int k = 0; k < H_DIM; k++) s += xs[k] * W1[(size_t)k * 1024 + j];
    float h = gelu_f(s * (1.0f / (float)S_SZ) + bias[j]);
    hbuf[((net * 4 + b) << 10) + j] = h;
}

// ---------------------------------------------------------------------------
// ctx/task output scalar: sigmoid(h . W2 + b2) -> d_out
// grid (4 batches, 2 nets), 256 threads
// ---------------------------------------------------------------------------
__global__ __launch_bounds__(256) void ctx_task_out(const float* __restrict__ hbuf,
        const float* __restrict__ ctxW2, const float* __restrict__ ctxb2,
        const float* __restrict__ taskW2, const float* __restrict__ taskb2,
        float* __restrict__ dout) {
    int b = blockIdx.x, net = blockIdx.y;
    const float* W2 = net ? taskW2 : ctxW2;
    const float* h = hbuf + ((net * 4 + b) << 10);
    float s = 0.f;
    #pragma unroll
    for (int jj = 0; jj < 4; jj++) {
        int j = jj * 256 + threadIdx.x;
        s += h[j] * W2[j];
    }
    #pragma unroll
    for (int off = 32; off; off >>= 1) s += __shfl_down(s, off, 64);
    __shared__ float red[4];
    if ((threadIdx.x & 63) == 0) red[threadIdx.x >> 6] = s;
    __syncthreads();
    if (threadIdx.x == 0) {
        float tot = red[0] + red[1] + red[2] + red[3];
        float b2 = net ? taskb2[0] : ctxb2[0];
        dout[OUT_CTXC + net * 4 + b] = sigmoid_f(tot + b2);
    }
}

// ---------------------------------------------------------------------------
// Fused MLP GEMM: logit[m,p] += sum_n gelu( (X@W1)[m,n] + b1[n] + fixup ) * W2[n,p]
// 128x128 block tile, BK=16, 256 threads, 8x8 micro-tile (2x2 quadrants).
// FIXUP adds the H+3 "combined" columns as rank-3 per-row corrections:
//   h += tokc[m]*W1[2048,n] + cc[batch]*W1[2049,n] + tk[batch]*W1[2050,n]
// Partial second-layer dots are shuffle-reduced then atomicAdd'ed into
// out_logit (pre-initialized with b2 by init_ws).
// ---------------------------------------------------------------------------
template<int P, bool FIXUP>
__global__ __launch_bounds__(256) void mlp_gemm(
        const float* __restrict__ X, const float* __restrict__ W1,
        const float* __restrict__ b1, const float* __restrict__ W2,
        const float* __restrict__ tokc, const float* __restrict__ ccp,
        const float* __restrict__ tkp, float* __restrict__ out_logit, int N) {
    __shared__ float As[16][132];   // [k][m], +4 pad keeps 16B align, 2-way max
    __shared__ float Bs[16][132];   // [k][n]
    const int tid = threadIdx.x;
    const int tx = tid & 15;
    const int ty = tid >> 4;
    const int m0 = blockIdx.y * 128;
    const int n0 = blockIdx.x * 128;
    const int arow = tid >> 2;          // 0..63
    const int acol = (tid & 3) << 2;    // 0,4,8,12
    const int brow = tid >> 5;          // 0..7
    const int bcol = (tid & 31) << 2;   // 0..124

    float acc[8][8];
    #pragma unroll
    for (int i = 0; i < 8; i++)
        #pragma unroll
        for (int j = 0; j < 8; j++) acc[i][j] = 0.f;

    const float* Ap0 = X + (size_t)(m0 + arow) * K_DIM + acol;
    const float* Ap1 = Ap0 + (size_t)64 * K_DIM;
    const float* Bp  = W1 + (size_t)brow * N + n0 + bcol;

    for (int k0 = 0; k0 < K_DIM; k0 += 16) {
        float4 a0  = *(const float4*)(Ap0 + k0);
        float4 a1  = *(const float4*)(Ap1 + k0);
        float4 b0  = *(const float4*)(Bp + (size_t)k0 * N);
        float4 b1v = *(const float4*)(Bp + (size_t)(k0 + 8) * N);
        __syncthreads();
        As[acol + 0][arow] = a0.x;  As[acol + 1][arow] = a0.y;
        As[acol + 2][arow] = a0.z;  As[acol + 3][arow] = a0.w;
        As[acol + 0][arow + 64] = a1.x;  As[acol + 1][arow + 64] = a1.y;
        As[acol + 2][arow + 64] = a1.z;  As[acol + 3][arow + 64] = a1.w;
        *(float4*)&Bs[brow][bcol] = b0;
        *(float4*)&Bs[brow + 8][bcol] = b1v;
        __syncthreads();
        #pragma unroll
        for (int kk = 0; kk < 16; kk++) {
            float4 aA = *(const float4*)&As[kk][ty << 2];
            float4 aB = *(const float4*)&As[kk][64 + (ty << 2)];
            float4 bA = *(const float4*)&Bs[kk][tx << 2];
            float4 bB = *(const float4*)&Bs[kk][64 + (tx << 2)];
            float a[8]  = {aA.x, aA.y, aA.z, aA.w, aB.x, aB.y, aB.z, aB.w};
            float bb[8] = {bA.x, bA.y, bA.z, bA.w, bB.x, bB.y, bB.z, bB.w};
            #pragma unroll
            for (int i = 0; i < 8; i++)
                #pragma unroll
                for (int j = 0; j < 8; j++)
                    acc[i][j] = fmaf(a[i], bb[j], acc[i][j]);
        }
    }

    int cols[8], rows[8];
    #pragma unroll
    for (int j = 0; j < 8; j++) cols[j] = n0 + (tx << 2) + (j & 3) + ((j >> 2) << 6);
    #pragma unroll
    for (int i = 0; i < 8; i++) rows[i] = m0 + (ty << 2) + (i & 3) + ((i >> 2) << 6);

    float biasv[8];
    #pragma unroll
    for (int j = 0; j < 8; j++) biasv[j] = b1[cols[j]];
    float f48[8], f49[8], f50[8];
    float ccv = 0.f, tkv = 0.f;
    if (FIXUP) {
        int batch = m0 >> 12;           // 4096 rows per batch, m0 % 4096 aligned
        ccv = ccp[batch];
        tkv = tkp[batch];
        #pragma unroll
        for (int j = 0; j < 8; j++) {
            f48[j] = W1[(size_t)2048 * N + cols[j]];
            f49[j] = W1[(size_t)2049 * N + cols[j]];
            f50[j] = W1[(size_t)2050 * N + cols[j]];
        }
    }
    #pragma unroll
    for (int i = 0; i < 8; i++) {
        float tc = FIXUP ? tokc[rows[i]] : 0.f;
        #pragma unroll
        for (int j = 0; j < 8; j++) {
            float h = acc[i][j] + biasv[j];
            if (FIXUP) h += tc * f48[j] + ccv * f49[j] + tkv * f50[j];
            acc[i][j] = gelu_f(h);
        }
    }
    #pragma unroll
    for (int p = 0; p < P; p++) {
        float w2v[8];
        #pragma unroll
        for (int j = 0; j < 8; j++) w2v[j] = W2[(size_t)cols[j] * P + p];
        #pragma unroll
        for (int i = 0; i < 8; i++) {
            float s = 0.f;
            #pragma unroll
            for (int j = 0; j < 8; j++) s = fmaf(acc[i][j], w2v[j], s);
            s += __shfl_xor(s, 1, 64);
            s += __shfl_xor(s, 2, 64);
            s += __shfl_xor(s, 4, 64);
            s += __shfl_xor(s, 8, 64);
            if (tx == 0) atomicAdd(&out_logit[(size_t)rows[i] * P + p], s);
        }
    }
}

// ---------------------------------------------------------------------------
// sigmoid on tok/eff logits -> token_complexity, efficiency_ratio
// ---------------------------------------------------------------------------
__global__ __launch_bounds__(256) void finalize1(const float* __restrict__ ws,
                                                 float* __restrict__ dout) {
    int r = blockIdx.x * 256 + threadIdx.x;   // 16384
    dout[OUT_TOKC + r] = sigmoid_f(ws[WS_TOKL + r]);
    dout[OUT_EFF + r]  = sigmoid_f(ws[WS_EFFL + r]);
}

// ---------------------------------------------------------------------------
// softmax on sup (4) and dep (8) logits; mask = (w > 0.2) * eff
// ---------------------------------------------------------------------------
__global__ __launch_bounds__(256) void finalize2(const float* __restrict__ ws,
                                                 float* __restrict__ dout) {
    int r = blockIdx.x * 256 + threadIdx.x;   // 16384
    const float* sl = ws + WS_SUPL + (size_t)r * 4;
    float l[4];
    #pragma unroll
    for (int i = 0; i < 4; i++) l[i] = sl[i];
    float mx = fmaxf(fmaxf(l[0], l[1]), fmaxf(l[2], l[3]));
    float e[4], sum = 0.f;
    #pragma unroll
    for (int i = 0; i < 4; i++) { e[i] = expf(l[i] - mx); sum += e[i]; }
    float inv = 1.0f / sum;
    float eff = dout[OUT_EFF + r];
    #pragma unroll
    for (int i = 0; i < 4; i++) {
        float w = e[i] * inv;
        dout[OUT_SUPW + (size_t)r * 4 + i] = w;
        dout[OUT_MASK + (size_t)r * 4 + i] = (w > 0.2f) ? eff : 0.f;
    }
    const float* dl = ws + WS_DEPL + (size_t)r * 8;
    float d[8];
    #pragma unroll
    for (int i = 0; i < 8; i++) d[i] = dl[i];
    float mx2 = d[0];
    #pragma unroll
    for (int i = 1; i < 8; i++) mx2 = fmaxf(mx2, d[i]);
    float sum2 = 0.f;
    #pragma unroll
    for (int i = 0; i < 8; i++) { d[i] = expf(d[i] - mx2); sum2 += d[i]; }
    float inv2 = 1.0f / sum2;
    #pragma unroll
    for (int i = 0; i < 8; i++)
        dout[OUT_DEPTH + (size_t)r * 8 + i] = d[i] * inv2;
}

// ---------------------------------------------------------------------------
extern "C" void kernel_launch(void* const* d_in, const int* in_sizes, int n_in,
                              void* d_out, int out_size, void* d_ws, size_t ws_size,
                              hipStream_t stream) {
    const float* X      = (const float*)d_in[0];
    const float* tokW1  = (const float*)d_in[1];
    const float* tokb1  = (const float*)d_in[2];
    const float* tokW2  = (const float*)d_in[3];
    const float* tokb2  = (const float*)d_in[4];
    const float* ctxW1  = (const float*)d_in[5];
    const float* ctxb1  = (const float*)d_in[6];
    const float* ctxW2  = (const float*)d_in[7];
    const float* ctxb2  = (const float*)d_in[8];
    const float* taskW1 = (const float*)d_in[9];
    const float* taskb1 = (const float*)d_in[10];
    const float* taskW2 = (const float*)d_in[11];
    const float* taskb2 = (const float*)d_in[12];
    const float* effW1  = (const float*)d_in[13];
    const float* effb1  = (const float*)d_in[14];
    const float* effW2  = (const float*)d_in[15];
    const float* effb2  = (const float*)d_in[16];
    const float* supW1  = (const float*)d_in[17];
    const float* supb1  = (const float*)d_in[18];
    const float* supW2  = (const float*)d_in[19];
    const float* supb2  = (const float*)d_in[20];
    const float* depW1  = (const float*)d_in[21];
    const float* depb1  = (const float*)d_in[22];
    const float* depW2  = (const float*)d_in[23];
    const float* depb2  = (const float*)d_in[24];
    float* out = (float*)d_out;
    float* ws  = (float*)d_ws;

    init_ws<<<(WS_TOTAL + 255) / 256, 256, 0, stream>>>(ws, tokb2, effb2, supb2, depb2);
    mean_kernel<<<dim3(8, 32, 4), 256, 0, stream>>>(X, ws + WS_CTXSUM);
    ctx_task_h<<<dim3(4, 4, 2), 256, 0, stream>>>(ws + WS_CTXSUM, ctxW1, ctxb1,
                                                  taskW1, taskb1, ws + WS_HBUF);
    ctx_task_out<<<dim3(4, 2), 256, 0, stream>>>(ws + WS_HBUF, ctxW2, ctxb2,
                                                 taskW2, taskb2, out);
    mlp_gemm<1, false><<<dim3(8, 128), 256, 0, stream>>>(
        X, tokW1, tokb1, tokW2, nullptr, nullptr, nullptr, ws + WS_TOKL, 1024);
    mlp_gemm<1, false><<<dim3(8, 128), 256, 0, stream>>>(
        X, effW1, effb1, effW2, nullptr, nullptr, nullptr, ws + WS_EFFL, 1024);
    finalize1<<<64, 256, 0, stream>>>(ws, out);
    mlp_gemm<4, true><<<dim3(16, 128), 256, 0, stream>>>(
        X, supW1, supb1, supW2, out + OUT_TOKC, out + OUT_CTXC, out + OUT_TASKC,
        ws + WS_SUPL, 2048);
    mlp_gemm<8, true><<<dim3(16, 128), 256, 0, stream>>>(
        X, depW1, depb1, depW2, out + OUT_TOKC, out + OUT_CTXC, out + OUT_TASKC,
        ws + WS_DEPL, 2048);
    finalize2<<<64, 256, 0, stream>>>(ws, out);
}

// Round 3
// 3195.777 us; speedup vs baseline: 2.0973x; 2.0973x over previous
//
#include <hip/hip_runtime.h>
#include <math.h>

// Problem geometry
#define B_SZ 4
#define S_SZ 4096
#define H_DIM 2048
#define M_TOT (B_SZ * S_SZ)   // 16384 token rows
#define K_DIM H_DIM           // 2048

// Output layout (flat floats, reference return order)
#define OUT_TOKC  0           // [4,4096,1]  16384
#define OUT_CTXC  16384       // [4,1]       4
#define OUT_TASKC 16388       // [4,1]       4
#define OUT_SUPW  16392       // [4,4096,4]  65536
#define OUT_DEPTH 81928       // [4,4096,8]  131072
#define OUT_EFF   213000      // [4,4096,1]  16384
#define OUT_MASK  229384      // [4,4096,4]  65536

// Workspace: fp32 logits area (float offsets), then bf16 split-weight buffers
#define WS_CTXSUM 0           // 8192
#define WS_HBUF   8192        // 8192
#define WS_TOKL   16384       // 16384  tok logits
#define WS_EFFL   32768       // 16384  eff logits
#define WS_SUPL   49152       // 65536  sup logits [M,4]
#define WS_DEPL   114688      // 131072 dep logits [M,8]
// repair machinery (borderline-threshold rows recomputed in fp32)
#define NF_MAX    1024
#define WS_FLAGCNT 245760     // 1 int
#define WS_FLAGIDX 245761     // NF_MAX ints
#define WS_RLOG    246788     // NF_MAX*4 floats (16B-aligned), init = supb2
#define WS_TOTAL   250884     // floats initialized by init_ws

// byte offsets for bf16 split weights (transposed to [N][2048])
#define WSB_TOKH  (1u<<20)
#define WSB_TOKL  (WSB_TOKH + 4194304u)   // 2048*1024*2 B each
#define WSB_EFFH  (WSB_TOKL + 4194304u)
#define WSB_EFFL  (WSB_EFFH + 4194304u)
#define WSB_SUPH  (WSB_EFFL + 4194304u)
#define WSB_SUPL  (WSB_SUPH + 8388608u)   // 2048*2048*2 B each
#define WSB_DEPH  (WSB_SUPL + 8388608u)
#define WSB_DEPL  (WSB_DEPH + 8388608u)

#define BAND 1e-3f

typedef __attribute__((ext_vector_type(8))) short bf16x8s;
typedef __attribute__((ext_vector_type(4))) float f32x4;

__device__ __forceinline__ float gelu_f(float x) {
    return 0.5f * x * (1.0f + erff(x * 0.70710678118654752440f));
}
__device__ __forceinline__ float sigmoid_f(float x) {
    return 1.0f / (1.0f + expf(-x));
}

// split fp32 -> (hi, lo) bf16 by bit truncation; lo captures next 8 mantissa bits.
__device__ __forceinline__ void split4(float4 v, unsigned* hi2, unsigned* lo2) {
    unsigned ux = __float_as_uint(v.x), uy = __float_as_uint(v.y);
    unsigned uz = __float_as_uint(v.z), uw = __float_as_uint(v.w);
    hi2[0] = (ux >> 16) | (uy & 0xffff0000u);
    hi2[1] = (uz >> 16) | (uw & 0xffff0000u);
    float lx = v.x - __uint_as_float(ux & 0xffff0000u);
    float ly = v.y - __uint_as_float(uy & 0xffff0000u);
    float lz = v.z - __uint_as_float(uz & 0xffff0000u);
    float lw = v.w - __uint_as_float(uw & 0xffff0000u);
    lo2[0] = (__float_as_uint(lx) >> 16) | (__float_as_uint(ly) & 0xffff0000u);
    lo2[1] = (__float_as_uint(lz) >> 16) | (__float_as_uint(lw) & 0xffff0000u);
}

// ---------------------------------------------------------------------------
__global__ __launch_bounds__(256) void init_ws(float* __restrict__ ws,
        const float* __restrict__ tokb2, const float* __restrict__ effb2,
        const float* __restrict__ supb2, const float* __restrict__ depb2) {
    int i = blockIdx.x * 256 + threadIdx.x;
    if (i >= WS_TOTAL) return;
    float v;
    if (i < WS_TOKL)        v = 0.0f;
    else if (i < WS_EFFL)   v = tokb2[0];
    else if (i < WS_SUPL)   v = effb2[0];
    else if (i < WS_DEPL)   v = supb2[(i - WS_SUPL) & 3];
    else if (i < WS_FLAGCNT) v = depb2[(i - WS_DEPL) & 7];
    else if (i < WS_RLOG)   v = 0.0f;                      // counter + indices (int 0)
    else                    v = supb2[(i - WS_RLOG) & 3];  // repair logit seeds
    ws[i] = v;
}

// ---------------------------------------------------------------------------
__global__ __launch_bounds__(256) void mean_kernel(const float* __restrict__ X,
                                                   float* __restrict__ ctxsum) {
    int h = blockIdx.x * 256 + threadIdx.x;
    int schunk = blockIdx.y;
    int b = blockIdx.z;
    const float* p = X + ((size_t)b * S_SZ + (size_t)schunk * 128) * H_DIM + h;
    float s = 0.f;
    #pragma unroll 4
    for (int i = 0; i < 128; i++) s += p[(size_t)i * H_DIM];
    atomicAdd(&ctxsum[b * H_DIM + h], s);
}

// ---------------------------------------------------------------------------
__global__ __launch_bounds__(256) void ctx_task_h(const float* __restrict__ ctxsum,
        const float* __restrict__ ctxW1, const float* __restrict__ ctxb1,
        const float* __restrict__ taskW1, const float* __restrict__ taskb1,
        float* __restrict__ hbuf) {
    int j = blockIdx.x * 256 + threadIdx.x;
    int b = blockIdx.y;
    int net = blockIdx.z;
    const float* W1   = net ? taskW1 : ctxW1;
    const float* bias = net ? taskb1 : ctxb1;
    const float* xs = ctxsum + b * H_DIM;
    float s = 0.f;
    #pragma unroll 8
    for (int k = 0; k < H_DIM; k++) s += xs[k] * W1[(size_t)k * 1024 + j];
    float h = gelu_f(s * (1.0f / (float)S_SZ) + bias[j]);
    hbuf[((net * 4 + b) << 10) + j] = h;
}

__global__ __launch_bounds__(256) void ctx_task_out(const float* __restrict__ hbuf,
        const float* __restrict__ ctxW2, const float* __restrict__ ctxb2,
        const float* __restrict__ taskW2, const float* __restrict__ taskb2,
        float* __restrict__ dout) {
    int b = blockIdx.x, net = blockIdx.y;
    const float* W2 = net ? taskW2 : ctxW2;
    const float* h = hbuf + ((net * 4 + b) << 10);
    float s = 0.f;
    #pragma unroll
    for (int jj = 0; jj < 4; jj++) s += h[jj * 256 + threadIdx.x] * W2[jj * 256 + threadIdx.x];
    #pragma unroll
    for (int off = 32; off; off >>= 1) s += __shfl_down(s, off, 64);
    __shared__ float red[4];
    if ((threadIdx.x & 63) == 0) red[threadIdx.x >> 6] = s;
    __syncthreads();
    if (threadIdx.x == 0) {
        float tot = red[0] + red[1] + red[2] + red[3];
        float b2 = net ? taskb2[0] : ctxb2[0];
        dout[OUT_CTXC + net * 4 + b] = sigmoid_f(tot + b2);
    }
}

// ---------------------------------------------------------------------------
// W1 [K=2048][N] fp32  ->  Wh/Wl [N][2048] bf16 (hi/lo split), 64x64 LDS tiles
// ---------------------------------------------------------------------------
__global__ __launch_bounds__(256) void transpose_split(const float* __restrict__ W1,
        unsigned short* __restrict__ Wh, unsigned short* __restrict__ Wl, int N) {
    __shared__ float T[64][68];
    int k0 = blockIdx.x * 64, n0 = blockIdx.y * 64;
    int t = threadIdx.x;
    int tk = t >> 4, tn = (t & 15) * 4;
    #pragma unroll
    for (int i = 0; i < 4; i++) {
        float4 v = *(const float4*)&W1[(size_t)(k0 + tk + i * 16) * N + n0 + tn];
        T[tk + i * 16][tn] = v.x;  T[tk + i * 16][tn + 1] = v.y;
        T[tk + i * 16][tn + 2] = v.z;  T[tk + i * 16][tn + 3] = v.w;
    }
    __syncthreads();
    int n = t >> 2, ks = (t & 3) * 16;
    unsigned hi[8], lo[8];
    #pragma unroll
    for (int j = 0; j < 16; j += 4) {
        float4 v = make_float4(T[ks + j][n], T[ks + j + 1][n],
                               T[ks + j + 2][n], T[ks + j + 3][n]);
        split4(v, &hi[j >> 1], &lo[j >> 1]);
    }
    size_t o = (size_t)(n0 + n) * 2048 + k0 + ks;
    *(uint4*)&Wh[o]     = make_uint4(hi[0], hi[1], hi[2], hi[3]);
    *(uint4*)&Wh[o + 8] = make_uint4(hi[4], hi[5], hi[6], hi[7]);
    *(uint4*)&Wl[o]     = make_uint4(lo[0], lo[1], lo[2], lo[3]);
    *(uint4*)&Wl[o + 8] = make_uint4(lo[4], lo[5], lo[6], lo[7]);
}

// ---------------------------------------------------------------------------
// Split-bf16 MFMA fused MLP GEMM (verified correct by round-2 outputs 0-5).
// ---------------------------------------------------------------------------
template<int P, bool FIXUP>
__global__ __launch_bounds__(256) void mfma_mlp(
        const float* __restrict__ X,
        const unsigned short* __restrict__ Wth, const unsigned short* __restrict__ Wtl,
        const float* __restrict__ W1fix, const float* __restrict__ b1,
        const float* __restrict__ W2,
        const float* __restrict__ tokc, const float* __restrict__ ccp,
        const float* __restrict__ tkp,
        float* __restrict__ out_logit, int N) {
    __shared__ unsigned short Ah[128 * 32], Al[128 * 32];
    __shared__ unsigned short Bh[128 * 32], Bl[128 * 32];

    const int t = threadIdx.x;
    const int lane = t & 63;
    const int w = t >> 6;
    const int wave_m = (w & 1) * 64;
    const int wave_n = (w >> 1) * 64;
    const int m0 = blockIdx.y * 128;
    const int n0 = blockIdx.x * 128;

    const int srow = t >> 1;
    const int skc  = (t & 1) * 2;
    const int swzw = (srow >> 1) & 3;
    const float* Xa = X + (size_t)(m0 + srow) * K_DIM + skc * 8;
    const unsigned short* BhG = Wth + (size_t)(n0 + srow) * K_DIM + skc * 8;
    const unsigned short* BlG = Wtl + (size_t)(n0 + srow) * K_DIM + skc * 8;
    unsigned short* AhW0 = &Ah[srow * 32 + ((skc ^ swzw) * 8)];
    unsigned short* AlW0 = &Al[srow * 32 + ((skc ^ swzw) * 8)];
    unsigned short* AhW1 = &Ah[srow * 32 + (((skc + 1) ^ swzw) * 8)];
    unsigned short* AlW1 = &Al[srow * 32 + (((skc + 1) ^ swzw) * 8)];
    unsigned short* BhW0 = &Bh[srow * 32 + ((skc ^ swzw) * 8)];
    unsigned short* BlW0 = &Bl[srow * 32 + ((skc ^ swzw) * 8)];
    unsigned short* BhW1 = &Bh[srow * 32 + (((skc + 1) ^ swzw) * 8)];
    unsigned short* BlW1 = &Bl[srow * 32 + (((skc + 1) ^ swzw) * 8)];

    const int lr = lane & 15;
    const int kq = lane >> 4;
    const int coff = ((kq ^ ((lr >> 1) & 3)) * 8);

    f32x4 acc[4][4];
    #pragma unroll
    for (int i = 0; i < 4; i++)
        #pragma unroll
        for (int j = 0; j < 4; j++) acc[i][j] = (f32x4){0.f, 0.f, 0.f, 0.f};

    for (int k0 = 0; k0 < K_DIM; k0 += 32) {
        float4 va0 = *(const float4*)(Xa + k0);
        float4 va1 = *(const float4*)(Xa + k0 + 4);
        float4 va2 = *(const float4*)(Xa + k0 + 8);
        float4 va3 = *(const float4*)(Xa + k0 + 12);
        uint4 vbh0 = *(const uint4*)(BhG + k0);
        uint4 vbh1 = *(const uint4*)(BhG + k0 + 8);
        uint4 vbl0 = *(const uint4*)(BlG + k0);
        uint4 vbl1 = *(const uint4*)(BlG + k0 + 8);

        unsigned h0[4], l0[4], h1[4], l1[4];
        split4(va0, &h0[0], &l0[0]);
        split4(va1, &h0[2], &l0[2]);
        split4(va2, &h1[0], &l1[0]);
        split4(va3, &h1[2], &l1[2]);

        __syncthreads();
        *(uint4*)AhW0 = make_uint4(h0[0], h0[1], h0[2], h0[3]);
        *(uint4*)AlW0 = make_uint4(l0[0], l0[1], l0[2], l0[3]);
        *(uint4*)AhW1 = make_uint4(h1[0], h1[1], h1[2], h1[3]);
        *(uint4*)AlW1 = make_uint4(l1[0], l1[1], l1[2], l1[3]);
        *(uint4*)BhW0 = vbh0;
        *(uint4*)BhW1 = vbh1;
        *(uint4*)BlW0 = vbl0;
        *(uint4*)BlW1 = vbl1;
        __syncthreads();

        bf16x8s ah[4], al[4];
        #pragma unroll
        for (int mt = 0; mt < 4; mt++) {
            int r = (wave_m + mt * 16 + lr) * 32 + coff;
            ah[mt] = *(const bf16x8s*)&Ah[r];
            al[mt] = *(const bf16x8s*)&Al[r];
        }
        #pragma unroll
        for (int nt = 0; nt < 4; nt++) {
            int rb = (wave_n + nt * 16 + lr) * 32 + coff;
            bf16x8s bh = *(const bf16x8s*)&Bh[rb];
            bf16x8s bl = *(const bf16x8s*)&Bl[rb];
            #pragma unroll
            for (int mt = 0; mt < 4; mt++) {
                acc[mt][nt] = __builtin_amdgcn_mfma_f32_16x16x32_bf16(ah[mt], bh, acc[mt][nt], 0, 0, 0);
                acc[mt][nt] = __builtin_amdgcn_mfma_f32_16x16x32_bf16(ah[mt], bl, acc[mt][nt], 0, 0, 0);
                acc[mt][nt] = __builtin_amdgcn_mfma_f32_16x16x32_bf16(al[mt], bh, acc[mt][nt], 0, 0, 0);
            }
        }
    }

    float ccv = 0.f, tkv = 0.f;
    if (FIXUP) {
        int batch = blockIdx.y >> 5;
        ccv = ccp[batch];
        tkv = tkp[batch];
    }
    #pragma unroll
    for (int mt = 0; mt < 4; mt++) {
        int mbase = m0 + wave_m + mt * 16 + kq * 4;
        f32x4 tc4 = (f32x4){0.f, 0.f, 0.f, 0.f};
        if (FIXUP) tc4 = *(const f32x4*)&tokc[mbase];
        #pragma unroll
        for (int nt = 0; nt < 4; nt++) {
            int n = n0 + wave_n + nt * 16 + lr;
            float bias = b1[n];
            float f1 = 0.f, f2 = 0.f, f3 = 0.f;
            if (FIXUP) {
                f1 = W1fix[(size_t)2048 * N + n];
                f2 = W1fix[(size_t)2049 * N + n];
                f3 = W1fix[(size_t)2050 * N + n];
            }
            #pragma unroll
            for (int j = 0; j < 4; j++) {
                float h = acc[mt][nt][j] + bias;
                if (FIXUP) h += tc4[j] * f1 + ccv * f2 + tkv * f3;
                acc[mt][nt][j] = gelu_f(h);
            }
        }
    }
    #pragma unroll
    for (int p = 0; p < P; p++) {
        float w2v[4];
        #pragma unroll
        for (int nt = 0; nt < 4; nt++)
            w2v[nt] = W2[(size_t)(n0 + wave_n + nt * 16 + lr) * P + p];
        #pragma unroll
        for (int mt = 0; mt < 4; mt++) {
            int mbase = m0 + wave_m + mt * 16 + kq * 4;
            #pragma unroll
            for (int j = 0; j < 4; j++) {
                float s = acc[mt][0][j] * w2v[0] + acc[mt][1][j] * w2v[1]
                        + acc[mt][2][j] * w2v[2] + acc[mt][3][j] * w2v[3];
                s += __shfl_xor(s, 1, 64);
                s += __shfl_xor(s, 2, 64);
                s += __shfl_xor(s, 4, 64);
                s += __shfl_xor(s, 8, 64);
                if (lr == p) atomicAdd(&out_logit[(size_t)(mbase + j) * P + p], s);
            }
        }
    }
}

// ---------------------------------------------------------------------------
__global__ __launch_bounds__(256) void finalize1(const float* __restrict__ ws,
                                                 float* __restrict__ dout) {
    int r = blockIdx.x * 256 + threadIdx.x;
    dout[OUT_TOKC + r] = sigmoid_f(ws[WS_TOKL + r]);
    dout[OUT_EFF + r]  = sigmoid_f(ws[WS_EFFL + r]);
}

// softmax + mask; flags rows whose sup_w is borderline-near 0.2 for fp32 repair
__global__ __launch_bounds__(256) void finalize2(float* __restrict__ ws,
                                                 float* __restrict__ dout) {
    int r = blockIdx.x * 256 + threadIdx.x;
    const float* sl = ws + WS_SUPL + (size_t)r * 4;
    float l[4];
    #pragma unroll
    for (int i = 0; i < 4; i++) l[i] = sl[i];
    float mx = fmaxf(fmaxf(l[0], l[1]), fmaxf(l[2], l[3]));
    float e[4], sum = 0.f;
    #pragma unroll
    for (int i = 0; i < 4; i++) { e[i] = expf(l[i] - mx); sum += e[i]; }
    float inv = 1.0f / sum;
    float eff = dout[OUT_EFF + r];
    bool flag = false;
    #pragma unroll
    for (int i = 0; i < 4; i++) {
        float wv = e[i] * inv;
        dout[OUT_SUPW + (size_t)r * 4 + i] = wv;
        dout[OUT_MASK + (size_t)r * 4 + i] = (wv > 0.2f) ? eff : 0.f;
        flag = flag || (fabsf(wv - 0.2f) < BAND);
    }
    if (flag) {
        int* cnt = (int*)(ws + WS_FLAGCNT);
        int* idx = (int*)(ws + WS_FLAGIDX);
        int slot = atomicAdd(cnt, 1);
        if (slot < NF_MAX) idx[slot] = r;
    }
    const float* dl = ws + WS_DEPL + (size_t)r * 8;
    float d[8];
    #pragma unroll
    for (int i = 0; i < 8; i++) d[i] = dl[i];
    float mx2 = d[0];
    #pragma unroll
    for (int i = 1; i < 8; i++) mx2 = fmaxf(mx2, d[i]);
    float sum2 = 0.f;
    #pragma unroll
    for (int i = 0; i < 8; i++) { d[i] = expf(d[i] - mx2); sum2 += d[i]; }
    float inv2 = 1.0f / sum2;
    #pragma unroll
    for (int i = 0; i < 8; i++)
        dout[OUT_DEPTH + (size_t)r * 8 + i] = d[i] * inv2;
}

// ---------------------------------------------------------------------------
// fp32 repair of sup logits for flagged rows.
// grid (16 j-tiles of 128, NF_MAX/8 row-chunks), 256 threads.
// wave 0,1: k in [0,1024); wave 2,3: k in [1024,2048); j = jtile*128 + (w&1)*64 + lane
// ---------------------------------------------------------------------------
__global__ __launch_bounds__(256) void repair_h(const float* __restrict__ X,
        const float* __restrict__ W1, const float* __restrict__ b1,
        const float* __restrict__ W2, const float* __restrict__ dout,
        const int* __restrict__ cntp, const int* __restrict__ idxp,
        float* __restrict__ rlog) {
    int cnt = *cntp; if (cnt > NF_MAX) cnt = NF_MAX;
    int rbase = blockIdx.y * 8;
    if (rbase >= cnt) return;
    int nr = cnt - rbase; if (nr > 8) nr = 8;

    __shared__ float Xs[8][2048];   // 64 KB
    __shared__ float HS[8][128];    // upper-k partial h

    const int t = threadIdx.x;
    const int w = t >> 6;
    const int lane = t & 63;
    const int joff = (w & 1) * 64 + lane;      // 0..127
    const int kh = w >> 1;                     // 0 or 1
    const int j = blockIdx.x * 128 + joff;

    int rows[8];
    #pragma unroll
    for (int rr = 0; rr < 8; rr++)
        rows[rr] = idxp[rbase + (rr < nr ? rr : 0)];

    for (int rr = 0; rr < nr; rr++) {
        const float4* src = (const float4*)(X + (size_t)rows[rr] * 2048);
        for (int c = t; c < 512; c += 256) ((float4*)Xs[rr])[c] = src[c];
    }
    for (int rr = nr; rr < 8; rr++)
        for (int c = t; c < 2048; c += 256) Xs[rr][c] = 0.f;
    __syncthreads();

    float h[8] = {0.f, 0.f, 0.f, 0.f, 0.f, 0.f, 0.f, 0.f};
    const float* Wcol = W1 + j;
    for (int k = kh * 1024; k < kh * 1024 + 1024; k += 4) {
        float w0 = Wcol[(size_t)(k + 0) * 2048];
        float w1 = Wcol[(size_t)(k + 1) * 2048];
        float w2 = Wcol[(size_t)(k + 2) * 2048];
        float w3 = Wcol[(size_t)(k + 3) * 2048];
        #pragma unroll
        for (int rr = 0; rr < 8; rr++) {
            float4 xv = *(const float4*)&Xs[rr][k];
            h[rr] = fmaf(xv.x, w0, h[rr]);
            h[rr] = fmaf(xv.y, w1, h[rr]);
            h[rr] = fmaf(xv.z, w2, h[rr]);
            h[rr] = fmaf(xv.w, w3, h[rr]);
        }
    }
    if (kh == 1) {
        #pragma unroll
        for (int rr = 0; rr < 8; rr++) HS[rr][joff] = h[rr];
    }
    __syncthreads();
    if (kh == 0) {
        float f1 = W1[(size_t)2048 * 2048 + j];
        float f2 = W1[(size_t)2049 * 2048 + j];
        float f3 = W1[(size_t)2050 * 2048 + j];
        float bj = b1[j];
        float4 w2v = *(const float4*)&W2[(size_t)j * 4];
        for (int rr = 0; rr < nr; rr++) {
            int r = rows[rr];
            float tc = dout[OUT_TOKC + r];
            float cc = dout[OUT_CTXC + (r >> 12)];
            float tk = dout[OUT_TASKC + (r >> 12)];
            float ht = h[rr] + HS[rr][joff] + tc * f1 + cc * f2 + tk * f3 + bj;
            float g = gelu_f(ht);
            float s0 = g * w2v.x, s1 = g * w2v.y, s2 = g * w2v.z, s3 = g * w2v.w;
            #pragma unroll
            for (int off = 1; off < 64; off <<= 1) {
                s0 += __shfl_xor(s0, off, 64);
                s1 += __shfl_xor(s1, off, 64);
                s2 += __shfl_xor(s2, off, 64);
                s3 += __shfl_xor(s3, off, 64);
            }
            if (lane == 0) {
                float* rl = rlog + (size_t)(rbase + rr) * 4;
                atomicAdd(&rl[0], s0);
                atomicAdd(&rl[1], s1);
                atomicAdd(&rl[2], s2);
                atomicAdd(&rl[3], s3);
            }
        }
    }
}

// overwrite supw + mask rows for flagged tokens from fp32 logits
__global__ __launch_bounds__(256) void repair_fin(const int* __restrict__ cntp,
        const int* __restrict__ idxp, const float* __restrict__ rlog,
        float* __restrict__ dout) {
    int cnt = *cntp; if (cnt > NF_MAX) cnt = NF_MAX;
    int slot = blockIdx.x * 256 + threadIdx.x;
    if (slot >= cnt) return;
    int r = idxp[slot];
    float l[4];
    #pragma unroll
    for (int i = 0; i < 4; i++) l[i] = rlog[(size_t)slot * 4 + i];
    float mx = fmaxf(fmaxf(l[0], l[1]), fmaxf(l[2], l[3]));
    float e[4], sum = 0.f;
    #pragma unroll
    for (int i = 0; i < 4; i++) { e[i] = expf(l[i] - mx); sum += e[i]; }
    float inv = 1.0f / sum;
    float eff = dout[OUT_EFF + r];
    #pragma unroll
    for (int i = 0; i < 4; i++) {
        float wv = e[i] * inv;
        dout[OUT_SUPW + (size_t)r * 4 + i] = wv;
        dout[OUT_MASK + (size_t)r * 4 + i] = (wv > 0.2f) ? eff : 0.f;
    }
}

// ---------------------------------------------------------------------------
extern "C" void kernel_launch(void* const* d_in, const int* in_sizes, int n_in,
                              void* d_out, int out_size, void* d_ws, size_t ws_size,
                              hipStream_t stream) {
    const float* X      = (const float*)d_in[0];
    const float* tokW1  = (const float*)d_in[1];
    const float* tokb1  = (const float*)d_in[2];
    const float* tokW2  = (const float*)d_in[3];
    const float* tokb2  = (const float*)d_in[4];
    const float* ctxW1  = (const float*)d_in[5];
    const float* ctxb1  = (const float*)d_in[6];
    const float* ctxW2  = (const float*)d_in[7];
    const float* ctxb2  = (const float*)d_in[8];
    const float* taskW1 = (const float*)d_in[9];
    const float* taskb1 = (const float*)d_in[10];
    const float* taskW2 = (const float*)d_in[11];
    const float* taskb2 = (const float*)d_in[12];
    const float* effW1  = (const float*)d_in[13];
    const float* effb1  = (const float*)d_in[14];
    const float* effW2  = (const float*)d_in[15];
    const float* effb2  = (const float*)d_in[16];
    const float* supW1  = (const float*)d_in[17];
    const float* supb1  = (const float*)d_in[18];
    const float* supW2  = (const float*)d_in[19];
    const float* supb2  = (const float*)d_in[20];
    const float* depW1  = (const float*)d_in[21];
    const float* depb1  = (const float*)d_in[22];
    const float* depW2  = (const float*)d_in[23];
    const float* depb2  = (const float*)d_in[24];
    float* out = (float*)d_out;
    float* ws  = (float*)d_ws;
    char*  wsb = (char*)d_ws;

    unsigned short* tokh = (unsigned short*)(wsb + WSB_TOKH);
    unsigned short* tokl = (unsigned short*)(wsb + WSB_TOKL);
    unsigned short* effh = (unsigned short*)(wsb + WSB_EFFH);
    unsigned short* effl = (unsigned short*)(wsb + WSB_EFFL);
    unsigned short* suph = (unsigned short*)(wsb + WSB_SUPH);
    unsigned short* supl = (unsigned short*)(wsb + WSB_SUPL);
    unsigned short* deph = (unsigned short*)(wsb + WSB_DEPH);
    unsigned short* depl = (unsigned short*)(wsb + WSB_DEPL);
    const int* cntp = (const int*)(ws + WS_FLAGCNT);
    const int* idxp = (const int*)(ws + WS_FLAGIDX);
    float* rlog = ws + WS_RLOG;

    init_ws<<<(WS_TOTAL + 255) / 256, 256, 0, stream>>>(ws, tokb2, effb2, supb2, depb2);
    mean_kernel<<<dim3(8, 32, 4), 256, 0, stream>>>(X, ws + WS_CTXSUM);
    ctx_task_h<<<dim3(4, 4, 2), 256, 0, stream>>>(ws + WS_CTXSUM, ctxW1, ctxb1,
                                                  taskW1, taskb1, ws + WS_HBUF);
    ctx_task_out<<<dim3(4, 2), 256, 0, stream>>>(ws + WS_HBUF, ctxW2, ctxb2,
                                                 taskW2, taskb2, out);
    transpose_split<<<dim3(32, 16), 256, 0, stream>>>(tokW1, tokh, tokl, 1024);
    transpose_split<<<dim3(32, 16), 256, 0, stream>>>(effW1, effh, effl, 1024);
    transpose_split<<<dim3(32, 32), 256, 0, stream>>>(supW1, suph, supl, 2048);
    transpose_split<<<dim3(32, 32), 256, 0, stream>>>(depW1, deph, depl, 2048);

    mfma_mlp<1, false><<<dim3(8, 128), 256, 0, stream>>>(
        X, tokh, tokl, nullptr, tokb1, tokW2, nullptr, nullptr, nullptr,
        ws + WS_TOKL, 1024);
    mfma_mlp<1, false><<<dim3(8, 128), 256, 0, stream>>>(
        X, effh, effl, nullptr, effb1, effW2, nullptr, nullptr, nullptr,
        ws + WS_EFFL, 1024);
    finalize1<<<64, 256, 0, stream>>>(ws, out);
    mfma_mlp<4, true><<<dim3(16, 128), 256, 0, stream>>>(
        X, suph, supl, supW1, supb1, supW2, out + OUT_TOKC, out + OUT_CTXC,
        out + OUT_TASKC, ws + WS_SUPL, 2048);
    mfma_mlp<8, true><<<dim3(16, 128), 256, 0, stream>>>(
        X, deph, depl, depW1, depb1, depW2, out + OUT_TOKC, out + OUT_CTXC,
        out + OUT_TASKC, ws + WS_DEPL, 2048);
    finalize2<<<64, 256, 0, stream>>>(ws, out);
    repair_h<<<dim3(16, NF_MAX / 8), 256, 0, stream>>>(
        X, supW1, supb1, supW2, out, cntp, idxp, rlog);
    repair_fin<<<NF_MAX / 256, 256, 0, stream>>>(cntp, idxp, rlog, out);
}